// Round 11
// baseline (250.470 us; speedup 1.0000x reference)
//
#include <hip/hip_runtime.h>
#include <hip/hip_fp16.h>

#define NN 40000
#define NE 640000
#define DF 128
#define NG 2000
#define NCH 157        // ceil(NN/256) node windows (256-node)
#define FILLB 625      // NE / (256*4) edge blocks, 4 edges/thread
#define GT_BLKS 625    // NN/64 -- 64-row GEMM tiles
#define GATB 10000     // gather blocks: (NN/16 node-groups) x 4 feature quarters
#define NCHUNK 16      // edge chunks
#define ECH 40000      // NE / NCHUNK
#define NOCT 8         // node eighths
#define QN 5120        // nodes per eighth (window-aligned: 20 windows of 256)
#define NPAD (NOCT * QN)   // 40960 padded nodes
#define NWIN 160       // NPAD / 256 windows
#define HISTB (NCHUNK * NOCT)  // 128 hist blocks
#define PREPB 192      // 64 slots-zero + 64 wt1 + 64 wt2
#define NSLOT 64       // BN-stat accumulation slots

typedef unsigned int u32;
typedef __attribute__((ext_vector_type(8))) short short8;
typedef __attribute__((ext_vector_type(4))) float floatx4;

// ---- bf16 helpers (packed u32: low 16 = even col, high = odd col) ----
__device__ inline float2 bf2_to_f2(u32 u) {
    return make_float2(__uint_as_float(u << 16), __uint_as_float(u & 0xffff0000u));
}
__device__ inline u32 f_to_bf(float f) {
    u32 u = __float_as_uint(f);
    return (u + 0x7fffu + ((u >> 16) & 1u)) >> 16;   // RNE
}
__device__ inline u32 pack_bf2(float a, float b) {
    return f_to_bf(a) | (f_to_bf(b) << 16);
}
__device__ inline float bf_to_f(short s) {
    return __uint_as_float(((u32)(unsigned short)s) << 16);
}
// packed col entry: low 16 = src index (<65536), high 16 = fp16(dis[src])
__device__ inline float colw_to_f(int cw) {
    return __half2float(__ushort_as_half((unsigned short)((u32)cw >> 16)));
}

// ---------------- MFMA GEMM core, 64-row tile ----------------
template<bool BF16IN, bool FUSE_BN>
__device__ __forceinline__ void gemm_core(const void* __restrict__ Xv, const unsigned short* __restrict__ wt,
                                          u32* __restrict__ outb, const float* __restrict__ slots,
                                          const float* __restrict__ gam, const float* __restrict__ bet,
                                          int bid, char* sbuf, float* sc, float* sh) {
    unsigned short* wlds = (unsigned short*)sbuf;
    unsigned short* clds = (unsigned short*)sbuf;
    int tid = threadIdx.x;
    int row0 = bid * 64;

    if (FUSE_BN) {
        if (tid < 128) {
            float s = 0.f, q = 0.f;
#pragma unroll
            for (int k = 0; k < NSLOT; k++) {
                s += slots[k * 256 + tid];
                q += slots[k * 256 + 128 + tid];
            }
            const float inv_n = 1.0f / (float)NN;
            float mu = s * inv_n;
            float va = fmaf(-mu, mu, q * inv_n);
            float a = gam[tid] * rsqrtf(va + 1e-5f);
            sc[tid] = a;
            sh[tid] = fmaf(-mu, a, bet[tid]);
        }
    }
    // stage W^T (pre-transposed bf16) into swizzled LDS: 8 uint4 per thread
    for (int i = tid; i < 2048; i += 256) {
        int c = i >> 4, s = i & 15;
        *(uint4*)&wlds[c * 128 + ((s ^ (c & 7)) << 3)] = ((const uint4*)wt)[i];
    }
    __syncthreads();

    int lane = tid & 63;
    int wave = tid >> 6;
    int qr = lane >> 4;
    int rl = lane & 15;

    int rA = row0 + wave * 16 + rl;   // < NN always (625*64 == NN)
    floatx4 acc[8];
#pragma unroll
    for (int b = 0; b < 8; b++) acc[b] = (floatx4){0.f, 0.f, 0.f, 0.f};
#pragma unroll
    for (int kb = 0; kb < 4; kb++) {
        int k0 = kb * 32 + qr * 8;
        short8 a0;
        if (!BF16IN) {
            const float* p0 = (const float*)Xv + (size_t)rA * DF + k0;
            float4 u0 = *(const float4*)p0, u1 = *(const float4*)(p0 + 4);
            float fa[8] = {u0.x, u0.y, u0.z, u0.w, u1.x, u1.y, u1.z, u1.w};
#pragma unroll
            for (int j = 0; j < 8; j++) a0[j] = (short)f_to_bf(fa[j]);
        } else {
            a0 = *(const short8*)((const u32*)Xv + (size_t)rA * 64 + (k0 >> 1));
            if (FUSE_BN) {
#pragma unroll
                for (int j = 0; j < 8; j++) {
                    float f0 = fmaxf(fmaf(bf_to_f(a0[j]), sc[k0 + j], sh[k0 + j]), 0.f);
                    a0[j] = (short)f_to_bf(f0);
                }
            }
        }
#pragma unroll
        for (int ct = 0; ct < 8; ct++) {
            int rowB = ct * 16 + rl;   // rowB&7 == rl&7
            short8 bfr = *(const short8*)&wlds[rowB * 128 + ((((kb << 2) + qr) ^ (rl & 7)) << 3)];
            acc[ct] = __builtin_amdgcn_mfma_f32_16x16x32_bf16(a0, bfr, acc[ct], 0, 0, 0);
        }
    }
    __syncthreads();
#pragma unroll
    for (int ct = 0; ct < 8; ct++)
#pragma unroll
        for (int r = 0; r < 4; r++) {
            int lr = wave * 16 + qr * 4 + r;
            int c = ct * 16 + rl;
            clds[lr * 128 + (((c >> 3) ^ (lr & 7)) << 3) + (c & 7)] = (unsigned short)f_to_bf(acc[ct][r]);
        }
    __syncthreads();
    for (int i = tid; i < 1024; i += 256) {
        int lr = i >> 4, s = i & 15;
        uint4 v = *(const uint4*)&clds[lr * 128 + ((s ^ (lr & 7)) << 3)];
        ((uint4*)(outb + (size_t)(row0 + lr) * 64))[s] = v;
    }
}

// ---------------- D1: prep (wt transpose + slots zero) || LDS-histogram count ----------------
__global__ __launch_bounds__(256) void k_prephist(const float* __restrict__ W1, const float* __restrict__ W2,
                                                  unsigned short* __restrict__ wt1, unsigned short* __restrict__ wt2,
                                                  float* __restrict__ slots0,
                                                  const int* __restrict__ dst,
                                                  int* __restrict__ degT, int* __restrict__ rank,
                                                  int* __restrict__ wsum) {
    __shared__ __align__(16) char sbuf[20480];   // hist only
    int bid = blockIdx.x, tid = threadIdx.x;
    if (bid < 64) {                     // slots0: 2*NSLOT*256 = 32768 floats
        slots0[bid * 512 + tid] = 0.f;
        slots0[bid * 512 + 256 + tid] = 0.f;
        return;
    }
    if (bid < 128) {                    // wt1[c*128+k] = bf16(W1[k][c]); coalesced writes
        int i = (bid - 64) * 256 + tid;
        wt1[i] = (unsigned short)f_to_bf(W1[(i & 127) * 128 + (i >> 7)]);
        return;
    }
    if (bid < PREPB) {                  // wt2 same
        int i = (bid - 128) * 256 + tid;
        wt2[i] = (unsigned short)f_to_bf(W2[(i & 127) * 128 + (i >> 7)]);
        return;
    }
    int hb = bid - PREPB;               // 0..127
    int c = hb >> 3, oct = hb & 7;
    int nlo = oct * QN;
    int* hist = (int*)sbuf;
    for (int i = tid; i < QN; i += 256) hist[i] = 0;
    __syncthreads();
    int ebase = c * ECH;
    const int4* dst4 = (const int4*)(dst + ebase);   // ECH=40000 = 10000 int4
    for (int i4 = tid; i4 < 10000; i4 += 256) {
        int4 d4 = dst4[i4];
        int e = ebase + i4 * 4;
        int t0 = d4.x - nlo, t1 = d4.y - nlo, t2 = d4.z - nlo, t3 = d4.w - nlo;
        if ((u32)t0 < (u32)QN) rank[e]     = atomicAdd(&hist[t0], 1);
        if ((u32)t1 < (u32)QN) rank[e + 1] = atomicAdd(&hist[t1], 1);
        if ((u32)t2 < (u32)QN) rank[e + 2] = atomicAdd(&hist[t2], 1);
        if ((u32)t3 < (u32)QN) rank[e + 3] = atomicAdd(&hist[t3], 1);
    }
    __syncthreads();
    for (int i = tid; i < QN; i += 256) degT[(size_t)c * NPAD + nlo + i] = hist[i];
    int wv = tid >> 6, lane = tid & 63;
    for (int lw = wv; lw < 20; lw += 4) {
        int v = hist[lw * 256 + lane] + hist[lw * 256 + 64 + lane]
              + hist[lw * 256 + 128 + lane] + hist[lw * 256 + 192 + lane];
        for (int off = 32; off > 0; off >>= 1) v += __shfl_down(v, off);
        if (lane == 0) wsum[c * NWIN + oct * 20 + lw] = v;
    }
}

// ---------------- D2: scan (157 blocks, hidden) || GEMM1 (625 blocks) ----------------
__global__ __launch_bounds__(256, 5) void k_scangemm(const int* __restrict__ degT, const int* __restrict__ wsum,
                                                     int* __restrict__ baseT,
                                                     int* __restrict__ row_ptr, float* __restrict__ dis,
                                                     const unsigned short* __restrict__ wt1,
                                                     const float* __restrict__ X, u32* __restrict__ outb) {
    __shared__ __align__(16) char sbuf[32768];
    int tid = threadIdx.x;
    int bid = blockIdx.x;
    if (bid < NCH) {
        int* red = (int*)sbuf;
        int* ls  = (int*)(sbuf + 1024);
        int wnd = bid;
        int part = 0;
        int wp = tid < NWIN ? tid : tid - NWIN;
        for (int idx = tid; idx < NCHUNK * NWIN; idx += 256) {
            if (wp < wnd) part += wsum[idx];
            wp += 96; if (wp >= NWIN) wp -= NWIN;  // 256 mod 160 = 96
        }
        red[tid] = part;
        int n = wnd * 256 + tid;    // < 40192 < NPAD, safe
        int run = 0;
#pragma unroll
        for (int c = 0; c < NCHUNK; c++) {
            int v = degT[(size_t)c * NPAD + n];
            baseT[(size_t)c * NPAD + n] = run;
            run += v;
        }
        int d = run;
        ls[tid] = d;
        __syncthreads();
#pragma unroll
        for (int off = 128; off > 0; off >>= 1) {
            if (tid < off) red[tid] += red[tid + off];
            __syncthreads();
        }
        int base = red[0];
#pragma unroll
        for (int off = 1; off < 256; off <<= 1) {
            int t = (tid >= off) ? ls[tid - off] : 0;
            __syncthreads();
            ls[tid] += t;
            __syncthreads();
        }
        if (n < NN) {
            int r = base + ls[tid] - d;   // global exclusive prefix
            row_ptr[n] = r;
            dis[n] = rsqrtf((float)(d + 1));
        }
        if (wnd == NCH - 1 && tid == 0) row_ptr[NN] = NE;
        return;
    }
    float* dummy = nullptr;
    gemm_core<false, false>(X, wt1, outb, nullptr, nullptr, nullptr,
                            bid - NCH, sbuf, dummy, dummy);
}

// ---------------- D3: CSR fill: atomic-free; slot = row_ptr[d] + baseT[chunk][d] + rank[e] ----------------
__global__ __launch_bounds__(256) void k_fill(const int* __restrict__ src, const int* __restrict__ dst,
                                              const int* __restrict__ rank, const int* __restrict__ row_ptr,
                                              const int* __restrict__ baseT,
                                              const float* __restrict__ dis, u32* __restrict__ col) {
    int i4 = blockIdx.x * 256 + threadIdx.x;   // < 160000
    int4 d4 = ((const int4*)dst)[i4];
    int4 s4 = ((const int4*)src)[i4];
    int4 r4 = ((const int4*)rank)[i4];
    int e = i4 * 4;
    int dd[4] = {d4.x, d4.y, d4.z, d4.w};
    int ss[4] = {s4.x, s4.y, s4.z, s4.w};
    int rr[4] = {r4.x, r4.y, r4.z, r4.w};
#pragma unroll
    for (int q = 0; q < 4; q++) {
        int c = (e + q) / ECH;
        u32 h = (u32)__half_as_ushort(__float2half(dis[ss[q]]));
        col[row_ptr[dd[q]] + baseT[(size_t)c * NPAD + dd[q]] + rr[q]] = (u32)ss[q] | (h << 16);
    }
}

__global__ __launch_bounds__(256, 4) void k_gemm2(const u32* __restrict__ Hb, const unsigned short* __restrict__ wt2,
                                                  u32* __restrict__ outb, const float* __restrict__ slots,
                                                  const float* __restrict__ gam, const float* __restrict__ bet) {
    __shared__ __align__(16) char sbuf[32768];
    __shared__ float sc[128], sh[128];
    gemm_core<true, true>(Hb, wt2, outb, slots, gam, bet, blockIdx.x, sbuf, sc, sh);
}

// ---------------- GCN aggregation: XCD-sharded feature quarters ----------------
// Block b -> XCD (b&7) [round-robin heuristic]; quarter = (b&7)>>1, so each XCD pair
// touches only 64B/row of Hb (2.6MB quarter) -> L2-resident -> src-row reuse (~16x)
// hits L2 instead of L3/HBM. Wave = 4 nodes x 16 lanes; shfl within 16-lane groups.
__global__ __launch_bounds__(256, 8) void k_gather(const u32* __restrict__ Hb, const int* __restrict__ row_ptr,
                                                   const u32* __restrict__ col, const float* __restrict__ dis,
                                                   const float* __restrict__ bias, u32* __restrict__ outb,
                                                   float* __restrict__ slots) {
    __shared__ float sred[4][16][2];
    __shared__ float qred[4][16][2];
    int tid = threadIdx.x;
    int lane = tid & 63;
    int wv = tid >> 6;
    int b = blockIdx.x;
    int quarter = (b & 7) >> 1;
    int ngrp = ((b >> 3) << 1) | (b & 1);   // [0,2500)
    int g = lane >> 4, r = lane & 15;
    int node = ngrp * 16 + wv * 4 + g;      // < 40000
    int f = quarter * 16 + r;               // u32 feature index [0,64)
    float di = dis[node];
    int lo = row_ptr[node], hi = row_ptr[node + 1];
    float2 acc;
    {
        float2 a = bf2_to_f2(Hb[(size_t)node * 64 + f]);
        acc = make_float2(a.x * di, a.y * di);   // di factored: final acc *= di
    }
    int lbase = lane & 48;                  // group shfl base
    for (int base = lo; base < hi; base += 16) {
        int m = hi - base; if (m > 16) m = 16;
        int cw = 0;
        if (r < m) cw = (int)col[base + r];
        int ng = (m + 3) >> 2;
        int c[4]; u32 u[4];
#pragma unroll
        for (int q = 0; q < 4; q++) {
            int idx = q < m ? q : 0;
            c[q] = __shfl(cw, lbase + idx);
            u[q] = Hb[(size_t)(c[q] & 0xffff) * 64 + f];
        }
        for (int gg = 1; gg < ng; gg++) {
            int c2[4]; u32 u2[4];
#pragma unroll
            for (int q = 0; q < 4; q++) {
                int ii = gg * 4 + q;
                int idx = ii < m ? ii : 0;
                c2[q] = __shfl(cw, lbase + idx);
                u2[q] = Hb[(size_t)(c2[q] & 0xffff) * 64 + f];
            }
#pragma unroll
            for (int q = 0; q < 4; q++) {
                int ii = (gg - 1) * 4 + q;
                float wq = ii < m ? colw_to_f(c[q]) : 0.f;
                float2 h = bf2_to_f2(u[q]);
                acc.x = fmaf(h.x, wq, acc.x);
                acc.y = fmaf(h.y, wq, acc.y);
            }
#pragma unroll
            for (int q = 0; q < 4; q++) { c[q] = c2[q]; u[q] = u2[q]; }
        }
#pragma unroll
        for (int q = 0; q < 4; q++) {
            int ii = (ng - 1) * 4 + q;
            float wq = ii < m ? colw_to_f(c[q]) : 0.f;
            float2 h = bf2_to_f2(u[q]);
            acc.x = fmaf(h.x, wq, acc.x);
            acc.y = fmaf(h.y, wq, acc.y);
        }
    }
    float2 bb = ((const float2*)bias)[f];
    acc.x = fmaf(acc.x, di, bb.x);
    acc.y = fmaf(acc.y, di, bb.y);
    outb[(size_t)node * 64 + f] = pack_bf2(acc.x, acc.y);
    // BN stats: reduce 4 groups via shfl_xor, 4 waves via LDS, then slot atomics
    float sx = acc.x, sy = acc.y, qx = acc.x * acc.x, qy = acc.y * acc.y;
    sx += __shfl_xor(sx, 16); sx += __shfl_xor(sx, 32);
    sy += __shfl_xor(sy, 16); sy += __shfl_xor(sy, 32);
    qx += __shfl_xor(qx, 16); qx += __shfl_xor(qx, 32);
    qy += __shfl_xor(qy, 16); qy += __shfl_xor(qy, 32);
    if (lane < 16) {
        sred[wv][r][0] = sx; sred[wv][r][1] = sy;
        qred[wv][r][0] = qx; qred[wv][r][1] = qy;
    }
    __syncthreads();
    if (tid < 32) {
        int rr = tid >> 1, side = tid & 1;
        float s = sred[0][rr][side] + sred[1][rr][side] + sred[2][rr][side] + sred[3][rr][side];
        float q = qred[0][rr][side] + qred[1][rr][side] + qred[2][rr][side] + qred[3][rr][side];
        int colx = 2 * (quarter * 16 + rr) + side;
        int slot = b & (NSLOT - 1);
        atomicAdd(&slots[slot * 256 + colx], s);
        atomicAdd(&slots[slot * 256 + 128 + colx], q);
    }
}

// ---------------- pool (BN2+ReLU) + fc1 + fc2 + fc3, 4 graphs per block ----------------
__global__ __launch_bounds__(256) void k_poolfc(const u32* __restrict__ Hb, const int* __restrict__ batch,
                                                const float* __restrict__ slots,
                                                const float* __restrict__ gam, const float* __restrict__ bet,
                                                const float* __restrict__ fc1w, const float* __restrict__ fc1b,
                                                const float* __restrict__ fc2w, const float* __restrict__ fc2b,
                                                const float* __restrict__ fc3w, const float* __restrict__ fc3b,
                                                float* __restrict__ out) {
    __shared__ float sc[128], sh[128];
    __shared__ float pooled[4][128];
    __shared__ float g1[4][256];
    __shared__ float g2[4][256];
    __shared__ int bnds[5];
    int tid = threadIdx.x;
    int gbase = blockIdx.x * 4;
    if (tid < 128) {
        float s = 0.f, q = 0.f;
#pragma unroll
        for (int k = 0; k < NSLOT; k++) {
            s += slots[k * 256 + tid];
            q += slots[k * 256 + 128 + tid];
        }
        const float inv_n = 1.0f / (float)NN;
        float mu = s * inv_n;
        float va = fmaf(-mu, mu, q * inv_n);
        float a = gam[tid] * rsqrtf(va + 1e-5f);
        sc[tid] = a;
        sh[tid] = fmaf(-mu, a, bet[tid]);
    } else if (tid < 133) {
        int target = gbase + (tid - 128);
        int a = 0, b = NN;
        while (a < b) { int m = (a + b) >> 1; if (batch[m] < target) a = m + 1; else b = m; }
        bnds[tid - 128] = a;
    }
    __syncthreads();
    {
        int g = tid >> 6, p = tid & 63;
        int lo = bnds[g], hi = bnds[g + 1];
        float a0 = 0.f, a1 = 0.f;
        float sc0 = sc[2 * p], sh0 = sh[2 * p], sc1 = sc[2 * p + 1], sh1 = sh[2 * p + 1];
        for (int i = lo; i < hi; i++) {
            float2 v = bf2_to_f2(Hb[(size_t)i * 64 + p]);
            a0 += fmaxf(fmaf(v.x, sc0, sh0), 0.f);
            a1 += fmaxf(fmaf(v.y, sc1, sh1), 0.f);
        }
        pooled[g][2 * p] = a0;
        pooled[g][2 * p + 1] = a1;
    }
    __syncthreads();
    {
        float x0 = 0.f, x1 = 0.f, x2 = 0.f, x3 = 0.f;
        for (int k = 0; k < 128; k++) {
            float wv = fc1w[k * 256 + tid];
            x0 = fmaf(pooled[0][k], wv, x0);
            x1 = fmaf(pooled[1][k], wv, x1);
            x2 = fmaf(pooled[2][k], wv, x2);
            x3 = fmaf(pooled[3][k], wv, x3);
        }
        float bb = fc1b[tid];
        g1[0][tid] = fmaxf(x0 + bb, 0.f);
        g1[1][tid] = fmaxf(x1 + bb, 0.f);
        g1[2][tid] = fmaxf(x2 + bb, 0.f);
        g1[3][tid] = fmaxf(x3 + bb, 0.f);
    }
    __syncthreads();
    {
        float x0 = 0.f, x1 = 0.f, x2 = 0.f, x3 = 0.f;
        for (int k = 0; k < 256; k++) {
            float wv = fc2w[k * 256 + tid];
            x0 = fmaf(g1[0][k], wv, x0);
            x1 = fmaf(g1[1][k], wv, x1);
            x2 = fmaf(g1[2][k], wv, x2);
            x3 = fmaf(g1[3][k], wv, x3);
        }
        float bb = fc2b[tid];
        g2[0][tid] = fmaxf(x0 + bb, 0.f);
        g2[1][tid] = fmaxf(x1 + bb, 0.f);
        g2[2][tid] = fmaxf(x2 + bb, 0.f);
        g2[3][tid] = fmaxf(x3 + bb, 0.f);
    }
    __syncthreads();
    {
        int lane = tid & 63, wv = tid >> 6;
        float s = fmaf(g2[wv][lane], fc3w[lane],
                  fmaf(g2[wv][64 + lane], fc3w[64 + lane],
                  fmaf(g2[wv][128 + lane], fc3w[128 + lane],
                       g2[wv][192 + lane] * fc3w[192 + lane])));
        for (int off = 32; off > 0; off >>= 1) s += __shfl_down(s, off);
        if (lane == 0) out[gbase + wv] = s + fc3b[0];
    }
}

extern "C" void kernel_launch(void* const* d_in, const int* in_sizes, int n_in,
                              void* d_out, int out_size, void* d_ws, size_t ws_size,
                              hipStream_t stream) {
    const float* x    = (const float*)d_in[0];
    const int*   ei   = (const int*)d_in[1];
    const int*   batch= (const int*)d_in[2];
    const float* W1   = (const float*)d_in[4];
    const float* b1   = (const float*)d_in[5];
    const float* W2   = (const float*)d_in[6];
    const float* b2   = (const float*)d_in[7];
    const float* bn1g = (const float*)d_in[8];
    const float* bn1b = (const float*)d_in[9];
    const float* bn2g = (const float*)d_in[10];
    const float* bn2b = (const float*)d_in[11];
    const float* fc1w = (const float*)d_in[12];
    const float* fc1b = (const float*)d_in[13];
    const float* fc2w = (const float*)d_in[14];
    const float* fc2b = (const float*)d_in[15];
    const float* fc3w = (const float*)d_in[16];
    const float* fc3b = (const float*)d_in[17];
    const int* src = ei;
    const int* dst = ei + NE;
    float* outp = (float*)d_out;

    char* w = (char*)d_ws;
    size_t o = 0;
    auto alloc = [&](size_t bytes) -> char* {
        char* p = w + o;
        o = (o + bytes + 255) & ~(size_t)255;
        return p;
    };
    int*   degT    = (int*)alloc((size_t)NCHUNK * NPAD * 4);   // 2.6MB, written fully
    int*   baseT   = (int*)alloc((size_t)NCHUNK * NPAD * 4);   // 2.6MB -> L2-resident in fill
    int*   wsum    = (int*)alloc((size_t)NCHUNK * NWIN * 4);
    float* slots0  = (float*)alloc((size_t)2 * NSLOT * 256 * 4);  // zeroed in D1
    int*   row_ptr = (int*)alloc((size_t)(NN + 1) * 4);
    int*   rank    = (int*)alloc((size_t)NE * 4);
    u32*   col     = (u32*)alloc((size_t)NE * 4);
    float* dis     = (float*)alloc((size_t)NN * 4);
    unsigned short* wt1 = (unsigned short*)alloc(128 * 128 * 2);
    unsigned short* wt2 = (unsigned short*)alloc(128 * 128 * 2);
    u32*   bufA    = (u32*)alloc((size_t)NN * 64 * 4);
    u32*   bufB    = (u32*)alloc((size_t)NN * 64 * 4);
    float* slotsA  = slots0;
    float* slotsB  = slots0 + NSLOT * 256;

    k_prephist<<<PREPB + HISTB, 256, 0, stream>>>(W1, W2, wt1, wt2, slots0,
                                                  dst, degT, rank, wsum);
    k_scangemm<<<NCH + GT_BLKS, 256, 0, stream>>>(degT, wsum, baseT, row_ptr, dis,
                                                  wt1, x, bufA);
    k_fill<<<FILLB, 256, 0, stream>>>(src, dst, rank, row_ptr, baseT, dis, col);
    k_gather<<<GATB, 256, 0, stream>>>(bufA, row_ptr, col, dis, b1, bufB, slotsA);
    k_gemm2<<<GT_BLKS, 256, 0, stream>>>(bufB, wt2, bufA, slotsA, bn1g, bn1b);
    k_gather<<<GATB, 256, 0, stream>>>(bufA, row_ptr, col, dis, b2, bufB, slotsB);
    k_poolfc<<<NG / 4, 256, 0, stream>>>(bufB, batch, slotsB, bn2g, bn2b,
                                         fc1w, fc1b, fc2w, fc2b, fc3w, fc3b, outp);
}

// Round 12
// 246.021 us; speedup vs baseline: 1.0181x; 1.0181x over previous
//
#include <hip/hip_runtime.h>
#include <hip/hip_fp16.h>

#define NN 40000
#define NE 640000
#define DF 128
#define NG 2000
#define NCH 157        // ceil(NN/256) node windows (256-node)
#define FILLB 625      // NE / (256*4) edge blocks, 4 edges/thread
#define GT_BLKS 625    // NN/64 -- 64-row GEMM tiles
#define NCHUNK 16      // edge chunks (small metadata -> baseT L2-resident in fill)
#define ECH 40000      // NE / NCHUNK
#define NOCT 8         // node eighths
#define QN 5120        // nodes per eighth (window-aligned: 20 windows of 256)
#define NPAD (NOCT * QN)   // 40960 padded nodes
#define NWIN 160       // NPAD / 256 windows
#define HISTB (NCHUNK * NOCT)  // 128 hist blocks (long-running; hide under GEMM1)

typedef unsigned int u32;
typedef __attribute__((ext_vector_type(8))) short short8;
typedef __attribute__((ext_vector_type(4))) float floatx4;

// ---- bf16 helpers (packed u32: low 16 = even col, high = odd col) ----
__device__ inline float2 bf2_to_f2(u32 u) {
    return make_float2(__uint_as_float(u << 16), __uint_as_float(u & 0xffff0000u));
}
__device__ inline u32 f_to_bf(float f) {
    u32 u = __float_as_uint(f);
    return (u + 0x7fffu + ((u >> 16) & 1u)) >> 16;   // RNE
}
__device__ inline u32 pack_bf2(float a, float b) {
    return f_to_bf(a) | (f_to_bf(b) << 16);
}
__device__ inline float bf_to_f(short s) {
    return __uint_as_float(((u32)(unsigned short)s) << 16);
}
// packed col entry: low 16 = src index (<65536), high 16 = fp16(dis[src])
__device__ inline float colw_to_f(int cw) {
    return __half2float(__ushort_as_half((unsigned short)((u32)cw >> 16)));
}

// ---------------- MFMA GEMM core, 64-row tile ----------------
// LDS sbuf = 32768 B: wlds = W^T bf16 [128 c][128 k], XOR-swizzled (16B chunk ^= row&7)
// -> stride 128, conflict-free. clds (C staging) same swizzle. Weights pre-transposed (k_prep).
template<bool BF16IN, bool FUSE_BN>
__device__ __forceinline__ void gemm_core(const void* __restrict__ Xv, const unsigned short* __restrict__ wt,
                                          u32* __restrict__ outb, const float* __restrict__ slots,
                                          const float* __restrict__ gam, const float* __restrict__ bet,
                                          int bid, char* sbuf, float* sc, float* sh) {
    unsigned short* wlds = (unsigned short*)sbuf;
    unsigned short* clds = (unsigned short*)sbuf;
    int tid = threadIdx.x;
    int row0 = bid * 64;

    if (FUSE_BN) {
        if (tid < 128) {
            float s = 0.f, q = 0.f;
            for (int k = 0; k < 64; k++) {
                s += slots[k * 256 + tid];
                q += slots[k * 256 + 128 + tid];
            }
            const float inv_n = 1.0f / (float)NN;
            float mu = s * inv_n;
            float va = fmaf(-mu, mu, q * inv_n);
            float a = gam[tid] * rsqrtf(va + 1e-5f);
            sc[tid] = a;
            sh[tid] = fmaf(-mu, a, bet[tid]);
        }
    }
    // stage W^T (pre-transposed bf16) into swizzled LDS: 8 uint4 per thread
    for (int i = tid; i < 2048; i += 256) {
        int c = i >> 4, s = i & 15;
        *(uint4*)&wlds[c * 128 + ((s ^ (c & 7)) << 3)] = ((const uint4*)wt)[i];
    }
    __syncthreads();

    int lane = tid & 63;
    int wave = tid >> 6;
    int qr = lane >> 4;
    int rl = lane & 15;

    int rA = row0 + wave * 16 + rl;   // < NN always (625*64 == NN)
    floatx4 acc[8];
#pragma unroll
    for (int b = 0; b < 8; b++) acc[b] = (floatx4){0.f, 0.f, 0.f, 0.f};
#pragma unroll
    for (int kb = 0; kb < 4; kb++) {
        int k0 = kb * 32 + qr * 8;
        short8 a0;
        if (!BF16IN) {
            const float* p0 = (const float*)Xv + (size_t)rA * DF + k0;
            float4 u0 = *(const float4*)p0, u1 = *(const float4*)(p0 + 4);
            float fa[8] = {u0.x, u0.y, u0.z, u0.w, u1.x, u1.y, u1.z, u1.w};
#pragma unroll
            for (int j = 0; j < 8; j++) a0[j] = (short)f_to_bf(fa[j]);
        } else {
            a0 = *(const short8*)((const u32*)Xv + (size_t)rA * 64 + (k0 >> 1));
            if (FUSE_BN) {
#pragma unroll
                for (int j = 0; j < 8; j++) {
                    float f0 = fmaxf(fmaf(bf_to_f(a0[j]), sc[k0 + j], sh[k0 + j]), 0.f);
                    a0[j] = (short)f_to_bf(f0);
                }
            }
        }
#pragma unroll
        for (int ct = 0; ct < 8; ct++) {
            int rowB = ct * 16 + rl;   // rowB&7 == rl&7
            short8 bfr = *(const short8*)&wlds[rowB * 128 + ((((kb << 2) + qr) ^ (rl & 7)) << 3)];
            acc[ct] = __builtin_amdgcn_mfma_f32_16x16x32_bf16(a0, bfr, acc[ct], 0, 0, 0);
        }
    }
    __syncthreads();
#pragma unroll
    for (int ct = 0; ct < 8; ct++)
#pragma unroll
        for (int r = 0; r < 4; r++) {
            int lr = wave * 16 + qr * 4 + r;
            int c = ct * 16 + rl;
            clds[lr * 128 + (((c >> 3) ^ (lr & 7)) << 3) + (c & 7)] = (unsigned short)f_to_bf(acc[ct][r]);
        }
    __syncthreads();
    for (int i = tid; i < 1024; i += 256) {
        int lr = i >> 4, s = i & 15;
        uint4 v = *(const uint4*)&clds[lr * 128 + ((s ^ (lr & 7)) << 3)];
        ((uint4*)(outb + (size_t)(row0 + lr) * 64))[s] = v;
    }
}

// ---------------- D0: prep -- wt1/wt2 transpose (bf16), zero slots ----------------
__global__ __launch_bounds__(256) void k_prep(const float* __restrict__ W1, const float* __restrict__ W2,
                                              unsigned short* __restrict__ wt1, unsigned short* __restrict__ wt2,
                                              float* __restrict__ slots0) {
    int bid = blockIdx.x, tid = threadIdx.x;
    if (bid < 64) {                     // slots0: 2*64*256 = 32768 floats
        slots0[bid * 512 + tid] = 0.f;
        slots0[bid * 512 + 256 + tid] = 0.f;
    } else if (bid < 128) {             // wt1[c*128+k] = bf16(W1[k][c]); coalesced writes
        int i = (bid - 64) * 256 + tid;
        wt1[i] = (unsigned short)f_to_bf(W1[(i & 127) * 128 + (i >> 7)]);
    } else {                            // wt2 same
        int i = (bid - 128) * 256 + tid;
        wt2[i] = (unsigned short)f_to_bf(W2[(i & 127) * 128 + (i >> 7)]);
    }
}

// ---------------- D1: LDS-histogram count (atomic-free CSR metadata) + GEMM1 ----------------
// Block (c,oct) streams chunk c's dst (160KB, L2-hot), LDS-hists its 5120-node eighth,
// writes rank[e], degT[c][.] slice, window sums wsum[c][w]. 128 long hist blocks hide
// under the 625 GEMM1 blocks in the same dispatch.
__global__ __launch_bounds__(256, 5) void k_countgemm(const int* __restrict__ dst,
                                                      int* __restrict__ degT, int* __restrict__ rank,
                                                      int* __restrict__ wsum,
                                                      const unsigned short* __restrict__ wt1,
                                                      const float* __restrict__ X, u32* __restrict__ outb) {
    __shared__ __align__(16) char sbuf[32768];   // hist (20480B) / gemm union
    int bid = blockIdx.x;
    int tid = threadIdx.x;
    if (bid < HISTB) {
        int c = bid >> 3, oct = bid & 7;
        int nlo = oct * QN;
        int* hist = (int*)sbuf;
        for (int i = tid; i < QN; i += 256) hist[i] = 0;
        __syncthreads();
        int ebase = c * ECH;
        const int4* dst4 = (const int4*)(dst + ebase);   // ECH=40000 = 10000 int4
        for (int i4 = tid; i4 < 10000; i4 += 256) {
            int4 d4 = dst4[i4];
            int e = ebase + i4 * 4;
            int t0 = d4.x - nlo, t1 = d4.y - nlo, t2 = d4.z - nlo, t3 = d4.w - nlo;
            if ((u32)t0 < (u32)QN) rank[e]     = atomicAdd(&hist[t0], 1);
            if ((u32)t1 < (u32)QN) rank[e + 1] = atomicAdd(&hist[t1], 1);
            if ((u32)t2 < (u32)QN) rank[e + 2] = atomicAdd(&hist[t2], 1);
            if ((u32)t3 < (u32)QN) rank[e + 3] = atomicAdd(&hist[t3], 1);
        }
        __syncthreads();
        // degT slice (coalesced, non-atomic)
        for (int i = tid; i < QN; i += 256) degT[(size_t)c * NPAD + nlo + i] = hist[i];
        // window sums: 20 windows x 256 entries
        int wv = tid >> 6, lane = tid & 63;
        for (int lw = wv; lw < 20; lw += 4) {
            int v = hist[lw * 256 + lane] + hist[lw * 256 + 64 + lane]
                  + hist[lw * 256 + 128 + lane] + hist[lw * 256 + 192 + lane];
            for (int off = 32; off > 0; off >>= 1) v += __shfl_down(v, off);
            if (lane == 0) wsum[c * NWIN + oct * 20 + lw] = v;
        }
        return;
    }
    gemm_core<false, false>(X, wt1, outb, nullptr, nullptr, nullptr,
                            bid - HISTB, sbuf, nullptr, nullptr);
}

// ---------------- D2: scan: 157 window blocks; base from wsum; emits row_ptr, dis, baseT ----------------
__global__ __launch_bounds__(256) void k_scan(const int* __restrict__ degT, const int* __restrict__ wsum,
                                              int* __restrict__ baseT,
                                              int* __restrict__ row_ptr, float* __restrict__ dis) {
    __shared__ int red[256];
    __shared__ int ls[256];
    int tid = threadIdx.x;
    int wnd = blockIdx.x;
    // cross-window base: sum wsum[c][w'] for all c, w' < wnd (incremental mod, no int-div)
    int part = 0;
    int wp = tid < NWIN ? tid : tid - NWIN;   // tid % 160 for tid<256
    for (int idx = tid; idx < NCHUNK * NWIN; idx += 256) {
        if (wp < wnd) part += wsum[idx];
        wp += 96; if (wp >= NWIN) wp -= NWIN;  // 256 mod 160 = 96
    }
    red[tid] = part;
    // per-node chunk prefix (16 iters, 2.6MB arrays: L2-friendly)
    int n = wnd * 256 + tid;    // < 40192 < NPAD, safe
    int run = 0;
#pragma unroll
    for (int c = 0; c < NCHUNK; c++) {
        int v = degT[(size_t)c * NPAD + n];
        baseT[(size_t)c * NPAD + n] = run;
        run += v;
    }
    int d = run;
    ls[tid] = d;
    __syncthreads();
#pragma unroll
    for (int off = 128; off > 0; off >>= 1) {
        if (tid < off) red[tid] += red[tid + off];
        __syncthreads();
    }
    int base = red[0];
#pragma unroll
    for (int off = 1; off < 256; off <<= 1) {
        int t = (tid >= off) ? ls[tid - off] : 0;
        __syncthreads();
        ls[tid] += t;
        __syncthreads();
    }
    if (n < NN) {
        int r = base + ls[tid] - d;   // global exclusive prefix
        row_ptr[n] = r;
        dis[n] = rsqrtf((float)(d + 1));
    }
    if (wnd == NCH - 1 && tid == 0) row_ptr[NN] = NE;
}

// ---------------- D3: CSR fill: atomic-free; slot = row_ptr[d] + baseT[chunk][d] + rank[e] ----------------
__global__ __launch_bounds__(256) void k_fill(const int* __restrict__ src, const int* __restrict__ dst,
                                              const int* __restrict__ rank, const int* __restrict__ row_ptr,
                                              const int* __restrict__ baseT,
                                              const float* __restrict__ dis, u32* __restrict__ col) {
    int i4 = blockIdx.x * 256 + threadIdx.x;   // < 160000
    int4 d4 = ((const int4*)dst)[i4];
    int4 s4 = ((const int4*)src)[i4];
    int4 r4 = ((const int4*)rank)[i4];
    int e = i4 * 4;
    int dd[4] = {d4.x, d4.y, d4.z, d4.w};
    int ss[4] = {s4.x, s4.y, s4.z, s4.w};
    int rr[4] = {r4.x, r4.y, r4.z, r4.w};
#pragma unroll
    for (int q = 0; q < 4; q++) {
        int c = (e + q) / ECH;   // magic-mul, no HW div
        u32 h = (u32)__half_as_ushort(__float2half(dis[ss[q]]));
        col[row_ptr[dd[q]] + baseT[(size_t)c * NPAD + dd[q]] + rr[q]] = (u32)ss[q] | (h << 16);
    }
}

__global__ __launch_bounds__(256, 4) void k_gemm2(const u32* __restrict__ Hb, const unsigned short* __restrict__ wt2,
                                                  u32* __restrict__ outb, const float* __restrict__ slots,
                                                  const float* __restrict__ gam, const float* __restrict__ bet) {
    __shared__ __align__(16) char sbuf[32768];
    __shared__ float sc[128], sh[128];
    gemm_core<true, true>(Hb, wt2, outb, slots, gam, bet, blockIdx.x, sbuf, sc, sh);
}

// ---------------- GCN aggregation: one wave/node, 4 nodes/block; BN-stats fused ----------------
__global__ __launch_bounds__(256, 8) void k_gather(const u32* __restrict__ Hb, const int* __restrict__ row_ptr,
                                                   const u32* __restrict__ col, const float* __restrict__ dis,
                                                   const float* __restrict__ bias, u32* __restrict__ outb,
                                                   float* __restrict__ slots) {
    __shared__ float sred[4][128];
    __shared__ float qred[4][128];
    int t = threadIdx.x & 63;                       // lane: cols 2t, 2t+1
    int wv = threadIdx.x >> 6;
    int node = blockIdx.x * 4 + wv;
    float di = dis[node];
    int lo = row_ptr[node], hi = row_ptr[node + 1];
    float2 acc;
    {
        float2 a = bf2_to_f2(Hb[(size_t)node * 64 + t]);
        acc = make_float2(a.x * di, a.y * di);   // di factored: final acc *= di
    }
    for (int base = lo; base < hi; base += 64) {
        int m = hi - base; if (m > 64) m = 64;
        int cw = 0;
        if (t < m) cw = (int)col[base + t];
        int ng = (m + 3) >> 2;
        int c[4]; u32 u[4];
#pragma unroll
        for (int q = 0; q < 4; q++) {
            int idx = q < m ? q : 0;
            c[q] = __shfl(cw, idx);
            u[q] = Hb[(size_t)(c[q] & 0xffff) * 64 + t];
        }
        for (int g = 1; g < ng; g++) {
            int c2[4]; u32 u2[4];
#pragma unroll
            for (int q = 0; q < 4; q++) {
                int ii = g * 4 + q;
                int idx = ii < m ? ii : 0;
                c2[q] = __shfl(cw, idx);
                u2[q] = Hb[(size_t)(c2[q] & 0xffff) * 64 + t];
            }
#pragma unroll
            for (int q = 0; q < 4; q++) {
                int ii = (g - 1) * 4 + q;
                float wq = ii < m ? colw_to_f(c[q]) : 0.f;
                float2 h = bf2_to_f2(u[q]);
                acc.x = fmaf(h.x, wq, acc.x);
                acc.y = fmaf(h.y, wq, acc.y);
            }
#pragma unroll
            for (int q = 0; q < 4; q++) { c[q] = c2[q]; u[q] = u2[q]; }
        }
#pragma unroll
        for (int q = 0; q < 4; q++) {
            int ii = (ng - 1) * 4 + q;
            float wq = ii < m ? colw_to_f(c[q]) : 0.f;
            float2 h = bf2_to_f2(u[q]);
            acc.x = fmaf(h.x, wq, acc.x);
            acc.y = fmaf(h.y, wq, acc.y);
        }
    }
    float2 b = ((const float2*)bias)[t];
    acc.x = fmaf(acc.x, di, b.x);
    acc.y = fmaf(acc.y, di, b.y);
    outb[(size_t)node * 64 + t] = pack_bf2(acc.x, acc.y);
    // BN stats (pre-BN activations, incl. bias): block reduce -> 64-slot atomics
    sred[wv][2 * t] = acc.x;     sred[wv][2 * t + 1] = acc.y;
    qred[wv][2 * t] = acc.x * acc.x; qred[wv][2 * t + 1] = acc.y * acc.y;
    __syncthreads();
    int tid = threadIdx.x;
    if (tid < 128) {
        float s = sred[0][tid] + sred[1][tid] + sred[2][tid] + sred[3][tid];
        float q = qred[0][tid] + qred[1][tid] + qred[2][tid] + qred[3][tid];
        int slot = blockIdx.x & 63;
        atomicAdd(&slots[slot * 256 + tid], s);
        atomicAdd(&slots[slot * 256 + 128 + tid], q);
    }
}

// ---------------- pool (BN2+ReLU) + fc1 + fc2 + fc3, 4 graphs per block ----------------
__global__ __launch_bounds__(256) void k_poolfc(const u32* __restrict__ Hb, const int* __restrict__ batch,
                                                const float* __restrict__ slots,
                                                const float* __restrict__ gam, const float* __restrict__ bet,
                                                const float* __restrict__ fc1w, const float* __restrict__ fc1b,
                                                const float* __restrict__ fc2w, const float* __restrict__ fc2b,
                                                const float* __restrict__ fc3w, const float* __restrict__ fc3b,
                                                float* __restrict__ out) {
    __shared__ float sc[128], sh[128];
    __shared__ float pooled[4][128];
    __shared__ float g1[4][256];
    __shared__ float g2[4][256];
    __shared__ int bnds[5];
    int tid = threadIdx.x;
    int gbase = blockIdx.x * 4;
    if (tid < 128) {
        float s = 0.f, q = 0.f;
        for (int k = 0; k < 64; k++) {
            s += slots[k * 256 + tid];
            q += slots[k * 256 + 128 + tid];
        }
        const float inv_n = 1.0f / (float)NN;
        float mu = s * inv_n;
        float va = fmaf(-mu, mu, q * inv_n);
        float a = gam[tid] * rsqrtf(va + 1e-5f);
        sc[tid] = a;
        sh[tid] = fmaf(-mu, a, bet[tid]);
    } else if (tid < 133) {
        int target = gbase + (tid - 128);
        int a = 0, b = NN;
        while (a < b) { int m = (a + b) >> 1; if (batch[m] < target) a = m + 1; else b = m; }
        bnds[tid - 128] = a;
    }
    __syncthreads();
    {
        int g = tid >> 6, p = tid & 63;
        int lo = bnds[g], hi = bnds[g + 1];
        float a0 = 0.f, a1 = 0.f;
        float sc0 = sc[2 * p], sh0 = sh[2 * p], sc1 = sc[2 * p + 1], sh1 = sh[2 * p + 1];
        for (int i = lo; i < hi; i++) {
            float2 v = bf2_to_f2(Hb[(size_t)i * 64 + p]);
            a0 += fmaxf(fmaf(v.x, sc0, sh0), 0.f);
            a1 += fmaxf(fmaf(v.y, sc1, sh1), 0.f);
        }
        pooled[g][2 * p] = a0;
        pooled[g][2 * p + 1] = a1;
    }
    __syncthreads();
    {
        float x0 = 0.f, x1 = 0.f, x2 = 0.f, x3 = 0.f;
        for (int k = 0; k < 128; k++) {
            float wv = fc1w[k * 256 + tid];
            x0 = fmaf(pooled[0][k], wv, x0);
            x1 = fmaf(pooled[1][k], wv, x1);
            x2 = fmaf(pooled[2][k], wv, x2);
            x3 = fmaf(pooled[3][k], wv, x3);
        }
        float bb = fc1b[tid];
        g1[0][tid] = fmaxf(x0 + bb, 0.f);
        g1[1][tid] = fmaxf(x1 + bb, 0.f);
        g1[2][tid] = fmaxf(x2 + bb, 0.f);
        g1[3][tid] = fmaxf(x3 + bb, 0.f);
    }
    __syncthreads();
    {
        float x0 = 0.f, x1 = 0.f, x2 = 0.f, x3 = 0.f;
        for (int k = 0; k < 256; k++) {
            float wv = fc2w[k * 256 + tid];
            x0 = fmaf(g1[0][k], wv, x0);
            x1 = fmaf(g1[1][k], wv, x1);
            x2 = fmaf(g1[2][k], wv, x2);
            x3 = fmaf(g1[3][k], wv, x3);
        }
        float bb = fc2b[tid];
        g2[0][tid] = fmaxf(x0 + bb, 0.f);
        g2[1][tid] = fmaxf(x1 + bb, 0.f);
        g2[2][tid] = fmaxf(x2 + bb, 0.f);
        g2[3][tid] = fmaxf(x3 + bb, 0.f);
    }
    __syncthreads();
    {
        int lane = tid & 63, wv = tid >> 6;
        float s = fmaf(g2[wv][lane], fc3w[lane],
                  fmaf(g2[wv][64 + lane], fc3w[64 + lane],
                  fmaf(g2[wv][128 + lane], fc3w[128 + lane],
                       g2[wv][192 + lane] * fc3w[192 + lane])));
        for (int off = 32; off > 0; off >>= 1) s += __shfl_down(s, off);
        if (lane == 0) out[gbase + wv] = s + fc3b[0];
    }
}

extern "C" void kernel_launch(void* const* d_in, const int* in_sizes, int n_in,
                              void* d_out, int out_size, void* d_ws, size_t ws_size,
                              hipStream_t stream) {
    const float* x    = (const float*)d_in[0];
    const int*   ei   = (const int*)d_in[1];
    const int*   batch= (const int*)d_in[2];
    const float* W1   = (const float*)d_in[4];
    const float* b1   = (const float*)d_in[5];
    const float* W2   = (const float*)d_in[6];
    const float* b2   = (const float*)d_in[7];
    const float* bn1g = (const float*)d_in[8];
    const float* bn1b = (const float*)d_in[9];
    const float* bn2g = (const float*)d_in[10];
    const float* bn2b = (const float*)d_in[11];
    const float* fc1w = (const float*)d_in[12];
    const float* fc1b = (const float*)d_in[13];
    const float* fc2w = (const float*)d_in[14];
    const float* fc2b = (const float*)d_in[15];
    const float* fc3w = (const float*)d_in[16];
    const float* fc3b = (const float*)d_in[17];
    const int* src = ei;
    const int* dst = ei + NE;
    float* outp = (float*)d_out;

    char* w = (char*)d_ws;
    size_t o = 0;
    auto alloc = [&](size_t bytes) -> char* {
        char* p = w + o;
        o = (o + bytes + 255) & ~(size_t)255;
        return p;
    };
    int*   degT    = (int*)alloc((size_t)NCHUNK * NPAD * 4);   // 2.6MB, written fully
    int*   baseT   = (int*)alloc((size_t)NCHUNK * NPAD * 4);   // 2.6MB -> L2-resident in fill
    int*   wsum    = (int*)alloc((size_t)NCHUNK * NWIN * 4);
    float* slots0  = (float*)alloc((size_t)2 * 64 * 256 * 4);  // zeroed in k_prep
    int*   row_ptr = (int*)alloc((size_t)(NN + 1) * 4);
    int*   rank    = (int*)alloc((size_t)NE * 4);
    u32*   col     = (u32*)alloc((size_t)NE * 4);
    float* dis     = (float*)alloc((size_t)NN * 4);
    unsigned short* wt1 = (unsigned short*)alloc(128 * 128 * 2);
    unsigned short* wt2 = (unsigned short*)alloc(128 * 128 * 2);
    u32*   bufA    = (u32*)alloc((size_t)NN * 64 * 4);
    u32*   bufB    = (u32*)alloc((size_t)NN * 64 * 4);
    float* slotsA  = slots0;
    float* slotsB  = slots0 + 64 * 256;

    k_prep<<<192, 256, 0, stream>>>(W1, W2, wt1, wt2, slots0);
    k_countgemm<<<HISTB + GT_BLKS, 256, 0, stream>>>(dst, degT, rank, wsum, wt1, x, bufA);
    k_scan<<<NCH, 256, 0, stream>>>(degT, wsum, baseT, row_ptr, dis);
    k_fill<<<FILLB, 256, 0, stream>>>(src, dst, rank, row_ptr, baseT, dis, col);
    k_gather<<<NN / 4, 256, 0, stream>>>(bufA, row_ptr, col, dis, b1, bufB, slotsA);
    k_gemm2<<<GT_BLKS, 256, 0, stream>>>(bufB, wt2, bufA, slotsA, bn1g, bn1b);
    k_gather<<<NN / 4, 256, 0, stream>>>(bufA, row_ptr, col, dis, b2, bufB, slotsB);
    k_poolfc<<<NG / 4, 256, 0, stream>>>(bufB, batch, slotsB, bn2g, bn2b,
                                         fc1w, fc1b, fc2w, fc2b, fc3w, fc3b, outp);
}